// Round 8
// baseline (194.069 us; speedup 1.0000x reference)
//
#include <hip/hip_runtime.h>
#include <math.h>

#define EPS 1e-6f

constexpr int B = 8, C = 3, H = 720, W = 1280;
constexpr int OPL = 5;           // outputs per lane: 256 * 5 == 1280 == W
constexpr int WIN = OPL + 20;    // d in [0,20) -> 25-source window per lane
constexpr int WP  = W + 32;      // padded cols (window overrun 1299 < 1312)
constexpr int RPB = 5;           // rows per block (software pipeline depth)
constexpr int NBLK = B * H / RPB;   // 1152 blocks: ALL resident (~4.5/CU), no tail
constexpr int NLD = W / 256;     // 5 staged cols per lane
// log2(1.414) in double precision
constexpr float K_LOG2 = 0.49978254377554356f;

static_assert(B * H % RPB == 0, "grid must tile rows exactly");

typedef float v2f __attribute__((ext_vector_type(2)));

// One block per 5 ROWS, software-pipelined (T14 issue-early/write-late).
// r5/r7 evidence: -25% VALU and -60% DS cycles both gave ~0 duration change ->
// the binding cost is EXPOSED VMEM LATENCY: stage(VMEM)/gather(VALU) phases
// alternate behind vmcnt(0)-draining barriers, and resident blocks are
// phase-correlated, so the CU idles ~45% of cycles. Fix: prefetch row r+1's 20
// global loads into REGISTERS right after the stage->gather barrier; first use
// is after the NEXT barrier, so the whole gather phase covers the latency.
// Stores go directly from accumulators (contiguous 1280B/wave/channel span;
// L2 write-combines; same DRAM bytes) -> 2 barriers/row, stores off-path.
// Numerics byte-identical to r7 (passed): AoS {c0*w,c1*w,c2*w,tx}; tent
// weights derived from tx = fl((float)x - d) -- the REFERENCE'S f32 grid
// (r4/r6 failed using finer-grid u=j-d: weight zero-sets flipped at knife-edge
// sources next to holes -> absmax 0.996). Do not refactor tx.
// LDS atomics measured lane-serialized (r1/r2) -> scatter stays dead.
// Reference's global 1.414^(-dmin) factor cancels in res/mask.
__global__ __launch_bounds__(256) void gather_kernel(const float* __restrict__ im,
                                                     const float* __restrict__ disp,
                                                     float* __restrict__ out) {
    __shared__ __attribute__((aligned(16))) float4 sv[WP];

    const int tid = (int)threadIdx.x;

    // pad written ONCE: the per-row write phase only touches x < W.
    // tx=-1e9 -> |u-k| huge -> bw=0; dd clamps to 20 -> w finite; contributes 0.
    if (tid < WP - W) sv[W + tid] = make_float4(0.f, 0.f, 0.f, -1.0e9f);

    const int row0 = (int)blockIdx.x * RPB;

    float pd[NLD], p0[NLD], p1[NLD], p2[NLD];    // prefetched row, in registers

    auto load_row = [&](int row) {
        const int b = row / H, y = row - b * H;
        const float* __restrict__ dr  = disp + (size_t)row * W;
        const float* __restrict__ im0 = im + ((size_t)(b * C + 0) * H + y) * W;
        const float* __restrict__ im1 = im + ((size_t)(b * C + 1) * H + y) * W;
        const float* __restrict__ im2 = im + ((size_t)(b * C + 2) * H + y) * W;
        #pragma unroll
        for (int i = 0; i < NLD; ++i) {          // coalesced b32, 4 streams
            const int x = tid + 256 * i;         // tid+1024 <= 1279 < W always
            pd[i] = dr[x];
            p0[i] = im0[x];
            p1[i] = im1[x];
            p2[i] = im2[x];
        }
    };

    load_row(row0);                              // prologue fill

    for (int r = 0; r < RPB; ++r) {
        const int row = row0 + r;

        // ---- write phase: premultiply + stage regs -> LDS ----
        #pragma unroll
        for (int i = 0; i < NLD; ++i) {
            const int x = tid + 256 * i;
            const float d  = pd[i];
            const float w  = exp2f(K_LOG2 * d);  // 1.414^d
            const float tx = (float)x - d;       // REF'S GRID -- do not refactor
            sv[x] = make_float4(p0[i] * w, p1[i] * w, p2[i] * w, tx);
        }
        __syncthreads();                         // stage visible to all waves

        // issue NEXT row's loads now; first use is after the next barrier,
        // so the gather below hides their latency.
        if (r + 1 < RPB) load_row(row + 1);

        // ---- gather: lane owns outputs [base, base+OPL) (identical to r7) ----
        const int base = tid * OPL;
        const float fx0 = (float)base;
        v2f a01[OPL], a23[OPL];                  // {c0,c1} and {c2,wsum}
        #pragma unroll
        for (int k = 0; k < OPL; ++k) {
            a01[k] = (v2f){0.f, 0.f};
            a23[k] = (v2f){0.f, 0.f};
        }

        #pragma unroll 5
        for (int j = 0; j < WIN; ++j) {
            const float4 v = sv[base + j];       // ds_read_b128, conflict-free
            const float tx = v.w;
            const float u  = tx - fx0;           // exact; ref-grid weights
            // dd == d rounded on the tx grid (Sterbenz); fminf guards pad.
            const float dd = fminf((float)(base + j) - tx, 20.0f);
            const float w  = exp2f(K_LOG2 * dd); // trans pipe
            const v2f v01 = {v.x, v.y};
            const v2f v23 = {v.z, w};
            #pragma unroll
            for (int k = 0; k < OPL; ++k) {
                // bit-matches ref's wa (floor(tx)==x) / wc (floor(tx)==x-1)
                const float bw = fmaxf(1.0f - fabsf(u - (float)k), 0.0f);
                a01[k] += v01 * bw;              // v_pk_fma_f32
                a23[k] += v23 * bw;
            }
        }
        __syncthreads();                         // sv reads done before next write

        // ---- direct store from accumulators (no LDS restage) ----
        const int b = row / H, y = row - b * H;
        float* __restrict__ o0 = out + ((size_t)(b * C + 0) * H + y) * W + base;
        float* __restrict__ o1 = out + ((size_t)(b * C + 1) * H + y) * W + base;
        float* __restrict__ o2 = out + ((size_t)(b * C + 2) * H + y) * W + base;
        #pragma unroll
        for (int k = 0; k < OPL; ++k) {
            const float inv = __builtin_amdgcn_rcpf(fmaxf(a23[k].y, EPS));
            o0[k] = a01[k].x * inv;
            o1[k] = a01[k].y * inv;
            o2[k] = a23[k].x * inv;
        }
    }
}

extern "C" void kernel_launch(void* const* d_in, const int* in_sizes, int n_in,
                              void* d_out, int out_size, void* d_ws, size_t ws_size,
                              hipStream_t stream) {
    const float* im   = (const float*)d_in[0];
    const float* disp = (const float*)d_in[1];
    float* out = (float*)d_out;
    (void)d_ws; (void)ws_size;

    gather_kernel<<<NBLK, 256, 0, stream>>>(im, disp, out);
}